// Round 9
// baseline (6606.449 us; speedup 1.0000x reference)
//
#include <hip/hip_runtime.h>
#include <float.h>

// Chamfer distance, fp32, N=M=16384 — MFMA 32x32, paired-frag min3 (R9).
//
// d(q,t) = u.t + |t|^2 + |q|^2, u=-2q, K=4 dot -> matrix cores via 2-level
// bf16 split, full product expansion packed in K=14 of 16 (absmax 0.0
// verified in R7/R8):
//   k:      0..2     3..5     6..7+8   9..11    12 13
//   A:    uh(xyz)  ul(xyz)  uh(xyz)  ul(xyz)    1  1
//   B:    th(xyz)  th(xyz)  tl(xyz)  tl(xyz)   wh wl
//
// R8 post-mortem: cd_main ~34us (total 81.7 minus the stable ~44.5us harness
// overhead: 40us 268MB workspace poison-fill + launches). 4x over the 8.5us
// math floor because each MFMA's 16 D-values need 16 dependent v_min_f32:
// VALU:MFMA = 4:1 cycles, every min chained to a just-retired MFMA. R9:
// process TWO B-frags per iteration and merge with v_min3_f32
// (min3(d_f0[i], d_f1[i], mm[i]) absorbs 2 new values/instr) -> min stream
// halves (floor 6.8 -> 3.4us), 4 independent MFMAs in flight per iter, plus
// 1-pair-ahead register prefetch of B to hide L2 latency.
//
// Layouts (guide §3, m74/m101-verified for 32x32):
//   A (32r x 16k): row = lane&31, k = 8*(lane>>5)+j
//   B (16k x 32c): col = lane&31, k = 8*(lane>>5)+j
//   D: col = lane&31, row = (reg&3) + 8*(reg>>2) + 4*(lane>>5)

#define NPTS 16384
constexpr int QPB   = 64;                 // queries per block (2 A-frags)
constexpr int NBLK  = NPTS / QPB;         // 256 blocks per direction
constexpr int NFRAG = NPTS / 32;          // 512 B-frags per point set
constexpr int FPW   = NFRAG / 8;          // 64 frags swept per wave
constexpr int SET_SHORTS = NFRAG * 512;   // 262144 shorts = 512 KB per set

typedef float f32x16 __attribute__((ext_vector_type(16)));
typedef short bf16x8 __attribute__((ext_vector_type(8)));

__device__ inline ushort bf16rne(float f) {
    uint u = __float_as_uint(f);
    u += 0x7fff + ((u >> 16) & 1);        // round-to-nearest-even
    return (ushort)(u >> 16);
}
__device__ inline float bf2f(ushort h) { return __uint_as_float(((uint)h) << 16); }

// Split both point sets into B-fragment layout: bt[set][frag][lane][8 bf16].
__global__ __launch_bounds__(512) void cd_prep(const float* __restrict__ gt,
                                               const float* __restrict__ gen,
                                               short* __restrict__ bt) {
    const int t   = blockIdx.x * 512 + threadIdx.x;   // 0..65535
    const int set = t >> 15;                          // 0: gt, 1: gen
    const int rem = t & 32767;
    const int h   = rem >> 14;                        // k-group 0/1
    const int p   = rem & (NPTS - 1);                 // point index
    const float* __restrict__ src = set ? gen : gt;

    const float x = src[3 * p + 0], y = src[3 * p + 1], z = src[3 * p + 2];
    const ushort hx = bf16rne(x), hy = bf16rne(y), hz = bf16rne(z);
    const ushort lx = bf16rne(x - bf2f(hx));
    const ushort ly = bf16rne(y - bf2f(hy));
    const ushort lz = bf16rne(z - bf2f(hz));
    const float w = fmaf(x, x, fmaf(y, y, z * z));
    const ushort wh = bf16rne(w), wl = bf16rne(w - bf2f(wh));

    bf16x8 v;
    if (h == 0)
        v = (bf16x8){(short)hx, (short)hy, (short)hz, (short)hx,
                     (short)hy, (short)hz, (short)lx, (short)ly};
    else
        v = (bf16x8){(short)lz, (short)lx, (short)ly, (short)lz,
                     (short)wh, (short)wl, (short)0, (short)0};
    *(bf16x8*)(bt + set * SET_SHORTS + (p >> 5) * 512 + (h * 32 + (p & 31)) * 8) = v;
}

__global__ __launch_bounds__(512, 4) void cd_main(const float* __restrict__ gt,
                                                  const float* __restrict__ gen,
                                                  const short* __restrict__ bt,
                                                  float* __restrict__ part) {
    const int dir = blockIdx.y;                    // 0: gt->gen, 1: gen->gt
    const float* __restrict__ Q = dir ? gen : gt;
    const short* __restrict__ BT = bt + (dir ? 0 : SET_SHORTS);  // opposite set

    __shared__ float wm[8][QPB];

    const int tid  = threadIdx.x;
    const int lane = tid & 63;
    const int wave = __builtin_amdgcn_readfirstlane(tid >> 6);

    // ---- 2 A-frags per wave (all waves share the same 64 queries). ----
    const int arow = lane & 31, kg = lane >> 5;
    const int qbase = blockIdx.x * QPB;
    bf16x8 a[2];
    #pragma unroll
    for (int f = 0; f < 2; ++f) {
        const int q = qbase + f * 32 + arow;
        const float x = Q[3 * q + 0], y = Q[3 * q + 1], z = Q[3 * q + 2];
        const float ux = -2.f * x, uy = -2.f * y, uz = -2.f * z;
        const ushort hx = bf16rne(ux), hy = bf16rne(uy), hz = bf16rne(uz);
        const ushort lx = bf16rne(ux - bf2f(hx));
        const ushort ly = bf16rne(uy - bf2f(hy));
        const ushort lz = bf16rne(uz - bf2f(hz));
        if (kg == 0)
            a[f] = (bf16x8){(short)hx, (short)hy, (short)hz, (short)lx,
                            (short)ly, (short)lz, (short)hx, (short)hy};
        else
            a[f] = (bf16x8){(short)hz, (short)lx, (short)ly, (short)lz,
                            (short)0x3f80, (short)0x3f80, (short)0, (short)0};
    }

    f32x16 mm0 = (f32x16)(FLT_MAX), mm1 = (f32x16)(FLT_MAX);
    const f32x16 zc = (f32x16)(0.f);

    // ---- Sweep this wave's 64 B-frags from L2, 2 per iteration, with
    //      1-pair-ahead register prefetch. ----
    const short* rb = BT + (wave * FPW) * 512 + lane * 8;
    bf16x8 b0 = *(const bf16x8*)(rb);
    bf16x8 b1 = *(const bf16x8*)(rb + 512);
    #pragma unroll 2
    for (int f2 = 0; f2 < FPW - 2; f2 += 2) {
        const bf16x8 n0 = *(const bf16x8*)(rb + (f2 + 2) * 512);
        const bf16x8 n1 = *(const bf16x8*)(rb + (f2 + 3) * 512);
        const f32x16 d00 = __builtin_amdgcn_mfma_f32_32x32x16_bf16(a[0], b0, zc, 0, 0, 0);
        const f32x16 d01 = __builtin_amdgcn_mfma_f32_32x32x16_bf16(a[0], b1, zc, 0, 0, 0);
        #pragma unroll
        for (int i = 0; i < 16; ++i)
            mm0[i] = fminf(fminf(d00[i], d01[i]), mm0[i]);   // -> v_min3_f32
        const f32x16 d10 = __builtin_amdgcn_mfma_f32_32x32x16_bf16(a[1], b0, zc, 0, 0, 0);
        const f32x16 d11 = __builtin_amdgcn_mfma_f32_32x32x16_bf16(a[1], b1, zc, 0, 0, 0);
        #pragma unroll
        for (int i = 0; i < 16; ++i)
            mm1[i] = fminf(fminf(d10[i], d11[i]), mm1[i]);
        b0 = n0; b1 = n1;
    }
    {   // tail pair
        const f32x16 d00 = __builtin_amdgcn_mfma_f32_32x32x16_bf16(a[0], b0, zc, 0, 0, 0);
        const f32x16 d01 = __builtin_amdgcn_mfma_f32_32x32x16_bf16(a[0], b1, zc, 0, 0, 0);
        const f32x16 d10 = __builtin_amdgcn_mfma_f32_32x32x16_bf16(a[1], b0, zc, 0, 0, 0);
        const f32x16 d11 = __builtin_amdgcn_mfma_f32_32x32x16_bf16(a[1], b1, zc, 0, 0, 0);
        #pragma unroll
        for (int i = 0; i < 16; ++i) {
            mm0[i] = fminf(fminf(d00[i], d01[i]), mm0[i]);
            mm1[i] = fminf(fminf(d10[i], d11[i]), mm1[i]);
        }
    }

    // ---- Cross-lane min over the 32 target-cols of each D row. ----
    #pragma unroll
    for (int i = 0; i < 16; ++i) {
        float v0 = mm0[i], v1 = mm1[i];
        #pragma unroll
        for (int off = 1; off <= 16; off <<= 1) {
            v0 = fminf(v0, __shfl_xor(v0, off, 64));
            v1 = fminf(v1, __shfl_xor(v1, off, 64));
        }
        const int row = (i & 3) + 8 * (i >> 2) + 4 * kg;
        if ((lane & 31) == 0) {
            wm[wave][row]      = v0;               // frag 0: queries qbase+row
            wm[wave][32 + row] = v1;               // frag 1: queries qbase+32+row
        }
    }
    __syncthreads();

    // ---- Merge the 8 wave-slices, add |q|^2, sum the block's 64 queries. ----
    if (tid < QPB) {
        float v = wm[0][tid];
        #pragma unroll
        for (int w = 1; w < 8; ++w) v = fminf(v, wm[w][tid]);
        const int q = qbase + tid;
        const float x = Q[3 * q + 0], y = Q[3 * q + 1], z = Q[3 * q + 2];
        v += fmaf(x, x, fmaf(y, y, z * z));
        #pragma unroll
        for (int off = 32; off > 0; off >>= 1) v += __shfl_down(v, off, 64);
        if (tid == 0) part[blockIdx.y * NBLK + blockIdx.x] = v;
    }
}

__global__ __launch_bounds__(512) void cd_reduce(const float* __restrict__ part,
                                                 float* __restrict__ out) {
    float v = part[threadIdx.x];                   // 512 partials, 512 threads
    #pragma unroll
    for (int off = 32; off > 0; off >>= 1) v += __shfl_down(v, off, 64);
    __shared__ float ws[8];
    const int lane = threadIdx.x & 63, w = threadIdx.x >> 6;
    if (lane == 0) ws[w] = v;
    __syncthreads();
    if (threadIdx.x == 0) {
        float s = 0.0f;
        #pragma unroll
        for (int i = 0; i < 8; ++i) s += ws[i];
        out[0] = s * (1.0f / (float)NPTS);
    }
}

extern "C" void kernel_launch(void* const* d_in, const int* in_sizes, int n_in,
                              void* d_out, int out_size, void* d_ws, size_t ws_size,
                              hipStream_t stream) {
    const float* gt  = (const float*)d_in[0];
    const float* gen = (const float*)d_in[1];
    short* bt        = (short*)d_ws;                       // 2 x 512 KB B-frags
    float* part      = (float*)((short*)d_ws + 2 * SET_SHORTS);  // 512 floats
    float* out       = (float*)d_out;

    cd_prep<<<128, 512, 0, stream>>>(gt, gen, bt);
    dim3 grid(NBLK, 2);                                    // 256 x 2 = 512 blocks
    cd_main<<<grid, 512, 0, stream>>>(gt, gen, bt, part);
    cd_reduce<<<1, 512, 0, stream>>>(part, out);
}

// Round 10
// 81.713 us; speedup vs baseline: 80.8499x; 80.8499x over previous
//
#include <hip/hip_runtime.h>
#include <float.h>

// Chamfer distance, fp32, N=M=16384 — MFMA 32x32, paired-frag min3 (R10).
//
// d(q,t) = u.t + |t|^2 + |q|^2, u=-2q, K=4 dot -> matrix cores via 2-level
// bf16 split, full product expansion packed in K=14 of 16 (absmax 0.0
// verified R7/R8):
//   k:      0..2     3..5     6..7+8   9..11    12 13
//   A:    uh(xyz)  ul(xyz)  uh(xyz)  ul(xyz)    1  1
//   B:    th(xyz)  th(xyz)  tl(xyz)  tl(xyz)   wh wl
//
// R9 post-mortem: explicit 2-deep prefetch + unroll-2 + duplicated tail put
// ~150 VGPRs of live state against launch_bounds(512,4)'s 128 cap -> the
// allocator spilled the f32x16 accumulators per-iteration (WRITE_SIZE 2GB,
// FETCH 15GB, 6.6ms). R10 keeps the min3 pairing (16 v_min3 per 2 MFMAs,
// halving R8's dominant VALU stream) but with in-loop loads (R8-proven),
// program-ordered d-pairs (only 32 d-VGPRs live), no forced unroll, no
// tail duplication. Live-set ~90 regs <= 128.
//
// Layouts (guide §3, m74/m101-verified for 32x32):
//   A (32r x 16k): row = lane&31, k = 8*(lane>>5)+j
//   B (16k x 32c): col = lane&31, k = 8*(lane>>5)+j
//   D: col = lane&31, row = (reg&3) + 8*(reg>>2) + 4*(lane>>5)

#define NPTS 16384
constexpr int QPB   = 64;                 // queries per block (2 A-frags)
constexpr int NBLK  = NPTS / QPB;         // 256 blocks per direction
constexpr int NFRAG = NPTS / 32;          // 512 B-frags per point set
constexpr int FPW   = NFRAG / 8;          // 64 frags swept per wave
constexpr int SET_SHORTS = NFRAG * 512;   // 262144 shorts = 512 KB per set

typedef float f32x16 __attribute__((ext_vector_type(16)));
typedef short bf16x8 __attribute__((ext_vector_type(8)));

__device__ inline ushort bf16rne(float f) {
    uint u = __float_as_uint(f);
    u += 0x7fff + ((u >> 16) & 1);        // round-to-nearest-even
    return (ushort)(u >> 16);
}
__device__ inline float bf2f(ushort h) { return __uint_as_float(((uint)h) << 16); }

// Split both point sets into B-fragment layout: bt[set][frag][lane][8 bf16].
__global__ __launch_bounds__(512) void cd_prep(const float* __restrict__ gt,
                                               const float* __restrict__ gen,
                                               short* __restrict__ bt) {
    const int t   = blockIdx.x * 512 + threadIdx.x;   // 0..65535
    const int set = t >> 15;                          // 0: gt, 1: gen
    const int rem = t & 32767;
    const int h   = rem >> 14;                        // k-group 0/1
    const int p   = rem & (NPTS - 1);                 // point index
    const float* __restrict__ src = set ? gen : gt;

    const float x = src[3 * p + 0], y = src[3 * p + 1], z = src[3 * p + 2];
    const ushort hx = bf16rne(x), hy = bf16rne(y), hz = bf16rne(z);
    const ushort lx = bf16rne(x - bf2f(hx));
    const ushort ly = bf16rne(y - bf2f(hy));
    const ushort lz = bf16rne(z - bf2f(hz));
    const float w = fmaf(x, x, fmaf(y, y, z * z));
    const ushort wh = bf16rne(w), wl = bf16rne(w - bf2f(wh));

    bf16x8 v;
    if (h == 0)
        v = (bf16x8){(short)hx, (short)hy, (short)hz, (short)hx,
                     (short)hy, (short)hz, (short)lx, (short)ly};
    else
        v = (bf16x8){(short)lz, (short)lx, (short)ly, (short)lz,
                     (short)wh, (short)wl, (short)0, (short)0};
    *(bf16x8*)(bt + set * SET_SHORTS + (p >> 5) * 512 + (h * 32 + (p & 31)) * 8) = v;
}

__global__ __launch_bounds__(512, 4) void cd_main(const float* __restrict__ gt,
                                                  const float* __restrict__ gen,
                                                  const short* __restrict__ bt,
                                                  float* __restrict__ part) {
    const int dir = blockIdx.y;                    // 0: gt->gen, 1: gen->gt
    const float* __restrict__ Q = dir ? gen : gt;
    const short* __restrict__ BT = bt + (dir ? 0 : SET_SHORTS);  // opposite set

    __shared__ float wm[8][QPB];

    const int tid  = threadIdx.x;
    const int lane = tid & 63;
    const int wave = __builtin_amdgcn_readfirstlane(tid >> 6);

    // ---- 2 A-frags per wave (all waves share the same 64 queries). ----
    const int arow = lane & 31, kg = lane >> 5;
    const int qbase = blockIdx.x * QPB;
    bf16x8 a[2];
    #pragma unroll
    for (int f = 0; f < 2; ++f) {
        const int q = qbase + f * 32 + arow;
        const float x = Q[3 * q + 0], y = Q[3 * q + 1], z = Q[3 * q + 2];
        const float ux = -2.f * x, uy = -2.f * y, uz = -2.f * z;
        const ushort hx = bf16rne(ux), hy = bf16rne(uy), hz = bf16rne(uz);
        const ushort lx = bf16rne(ux - bf2f(hx));
        const ushort ly = bf16rne(uy - bf2f(hy));
        const ushort lz = bf16rne(uz - bf2f(hz));
        if (kg == 0)
            a[f] = (bf16x8){(short)hx, (short)hy, (short)hz, (short)lx,
                            (short)ly, (short)lz, (short)hx, (short)hy};
        else
            a[f] = (bf16x8){(short)hz, (short)lx, (short)ly, (short)lz,
                            (short)0x3f80, (short)0x3f80, (short)0, (short)0};
    }

    f32x16 mm0 = (f32x16)(FLT_MAX), mm1 = (f32x16)(FLT_MAX);
    const f32x16 zc = (f32x16)(0.f);

    // ---- Sweep this wave's 64 B-frags from L2, 2 per step, min3-merged.
    //      In-loop loads (R8-proven); d-pairs consumed in program order so
    //      only one 32-reg pair is live at a time. ----
    const short* rb = BT + (wave * FPW) * 512 + lane * 8;
    for (int f2 = 0; f2 < FPW; f2 += 2) {
        const bf16x8 b0 = *(const bf16x8*)(rb + f2 * 512);
        const bf16x8 b1 = *(const bf16x8*)(rb + (f2 + 1) * 512);
        const f32x16 d00 = __builtin_amdgcn_mfma_f32_32x32x16_bf16(a[0], b0, zc, 0, 0, 0);
        const f32x16 d01 = __builtin_amdgcn_mfma_f32_32x32x16_bf16(a[0], b1, zc, 0, 0, 0);
        #pragma unroll
        for (int i = 0; i < 16; ++i)
            mm0[i] = fminf(fminf(d00[i], d01[i]), mm0[i]);   // -> v_min3_f32
        const f32x16 d10 = __builtin_amdgcn_mfma_f32_32x32x16_bf16(a[1], b0, zc, 0, 0, 0);
        const f32x16 d11 = __builtin_amdgcn_mfma_f32_32x32x16_bf16(a[1], b1, zc, 0, 0, 0);
        #pragma unroll
        for (int i = 0; i < 16; ++i)
            mm1[i] = fminf(fminf(d10[i], d11[i]), mm1[i]);
    }

    // ---- Cross-lane min over the 32 target-cols of each D row. ----
    #pragma unroll
    for (int i = 0; i < 16; ++i) {
        float v0 = mm0[i], v1 = mm1[i];
        #pragma unroll
        for (int off = 1; off <= 16; off <<= 1) {
            v0 = fminf(v0, __shfl_xor(v0, off, 64));
            v1 = fminf(v1, __shfl_xor(v1, off, 64));
        }
        const int row = (i & 3) + 8 * (i >> 2) + 4 * kg;
        if ((lane & 31) == 0) {
            wm[wave][row]      = v0;               // frag 0: queries qbase+row
            wm[wave][32 + row] = v1;               // frag 1: queries qbase+32+row
        }
    }
    __syncthreads();

    // ---- Merge the 8 wave-slices, add |q|^2, sum the block's 64 queries. ----
    if (tid < QPB) {
        float v = wm[0][tid];
        #pragma unroll
        for (int w = 1; w < 8; ++w) v = fminf(v, wm[w][tid]);
        const int q = qbase + tid;
        const float x = Q[3 * q + 0], y = Q[3 * q + 1], z = Q[3 * q + 2];
        v += fmaf(x, x, fmaf(y, y, z * z));
        #pragma unroll
        for (int off = 32; off > 0; off >>= 1) v += __shfl_down(v, off, 64);
        if (tid == 0) part[blockIdx.y * NBLK + blockIdx.x] = v;
    }
}

__global__ __launch_bounds__(512) void cd_reduce(const float* __restrict__ part,
                                                 float* __restrict__ out) {
    float v = part[threadIdx.x];                   // 512 partials, 512 threads
    #pragma unroll
    for (int off = 32; off > 0; off >>= 1) v += __shfl_down(v, off, 64);
    __shared__ float ws[8];
    const int lane = threadIdx.x & 63, w = threadIdx.x >> 6;
    if (lane == 0) ws[w] = v;
    __syncthreads();
    if (threadIdx.x == 0) {
        float s = 0.0f;
        #pragma unroll
        for (int i = 0; i < 8; ++i) s += ws[i];
        out[0] = s * (1.0f / (float)NPTS);
    }
}

extern "C" void kernel_launch(void* const* d_in, const int* in_sizes, int n_in,
                              void* d_out, int out_size, void* d_ws, size_t ws_size,
                              hipStream_t stream) {
    const float* gt  = (const float*)d_in[0];
    const float* gen = (const float*)d_in[1];
    short* bt        = (short*)d_ws;                       // 2 x 512 KB B-frags
    float* part      = (float*)((short*)d_ws + 2 * SET_SHORTS);  // 512 floats
    float* out       = (float*)d_out;

    cd_prep<<<128, 512, 0, stream>>>(gt, gen, bt);
    dim3 grid(NBLK, 2);                                    // 256 x 2 = 512 blocks
    cd_main<<<grid, 512, 0, stream>>>(gt, gen, bt, part);
    cd_reduce<<<1, 512, 0, stream>>>(part, out);
}